// Round 8
// baseline (1430.793 us; speedup 1.0000x reference)
//
#include <hip/hip_runtime.h>
#include <stdint.h>

typedef unsigned short u16;
typedef unsigned int u32;
typedef __attribute__((ext_vector_type(8))) short short8;
typedef __attribute__((ext_vector_type(4))) float f32x4;

#define TN 10000
#define TE 100000
#define TG 64
#define TH 512
#define EC 25000
#define NCH 4
#define PAD 128

static constexpr size_t A256(size_t x){ return (x+255)/256*256; }
constexpr size_t OFF_H    = 0;
constexpr size_t OFF_PQ   = A256(OFF_H    + (size_t)TN*512*4);
constexpr size_t OFF_HCAT = A256(OFF_PQ   + (size_t)TN*1024*2);
constexpr size_t OFF_AGGF = A256(OFF_HCAT + (size_t)TN*1024*2);
constexpr size_t OFF_MC   = A256(OFF_AGGF + (size_t)TN*512*4);   // u overlays here
constexpr size_t OFF_XD   = A256(OFF_MC   + (size_t)(EC+PAD)*512*2);
constexpr size_t OFF_WAB  = A256(OFF_XD   + (size_t)(EC+PAD)*768*2);
constexpr size_t OFF_W1D  = A256(OFF_WAB  + (size_t)2*1024*512*2);
constexpr size_t OFF_W2   = A256(OFF_W1D  + (size_t)2*512*768*2);
constexpr size_t OFF_WN1  = A256(OFF_W2   + (size_t)2*512*512*2);
constexpr size_t OFF_WN2  = A256(OFF_WN1  + (size_t)2*512*1024*2);
constexpr size_t OFF_RP   = A256(OFF_WN2  + (size_t)2*512*512*2);
constexpr size_t OFF_H0   = A256(OFF_RP   + (size_t)2*64*512*4);
constexpr size_t OFF_B2   = A256(OFF_H0   + (size_t)119*512*4);
constexpr size_t OFF_CNT  = A256(OFF_B2   + 512*4);
constexpr size_t OFF_SLOT = A256(OFF_CNT  + (size_t)TN*4);
constexpr size_t OFF_IPTR = A256(OFF_SLOT + (size_t)TN*4);
constexpr size_t OFF_NOD  = A256(OFF_IPTR + (size_t)(TN+1)*4);
constexpr size_t OFF_DST  = A256(OFF_NOD  + (size_t)(TE+PAD)*4);
constexpr size_t OFF_FDS  = A256(OFF_DST  + (size_t)(TE+PAD)*4);
constexpr size_t WS_NEED  = OFF_FDS + (size_t)(TE+PAD)*3*4;

__device__ __forceinline__ float bf2f(u16 u){ u32 x=((u32)u)<<16; float f; __builtin_memcpy(&f,&x,4); return f; }
__device__ __forceinline__ u16 f2bf(float f){ u32 x; __builtin_memcpy(&x,&f,4); x = x + 0x7fffu + ((x>>16)&1u); return (u16)(x>>16); }
__device__ __forceinline__ float siluf(float v){ return v*(1.0f/(1.0f+__expf(-v))); }

__device__ __forceinline__ void gld16(const void* g, void* l){
  __builtin_amdgcn_global_load_lds((const __attribute__((address_space(1))) u32*)g,
                                   (__attribute__((address_space(3))) u32*)l, 16, 0, 0);
}

__device__ __forceinline__ void blockReduce2(float& s, float& ss){
  for (int off=32; off>0; off>>=1){ s += __shfl_down(s,off,64); ss += __shfl_down(ss,off,64); }
  __shared__ float red[8];
  int lane = threadIdx.x&63, wave = threadIdx.x>>6;
  if (lane==0){ red[wave*2]=s; red[wave*2+1]=ss; }
  __syncthreads();
  s  = red[0]+red[2]+red[4]+red[6];
  ss = red[1]+red[3]+red[5]+red[7];
}

// ============ Edge GEMM: BN=512 (full width), BM=32, 512 threads / 8 waves ====
// C[M,512] = A[M,K] @ B[512,K]^T.  B-tile 512x32 (32KB) double-buffered, L2-hot.
// A-tile 32x32: TRIGA -> computed sinusoid emb (ds_write), else gld16.
// 2-deep counted-vmcnt pipeline, raw barriers, T2 K-granule XOR swizzle.
// EPI 1: silu(acc+bias)->bf16.  EPI 2: silu(acc+P[src]+Q[dst]+R[graph])->bf16.
template<int EPI, bool TRIGA>
__device__ __forceinline__ void gemm512_core(
    const u16* __restrict__ A, const float* __restrict__ fdS,
    const u16* __restrict__ B, int M, int K, int cbase,
    u16* __restrict__ Cb, const float* __restrict__ bias,
    const u16* __restrict__ PQ,
    const int* __restrict__ nodS, const int* __restrict__ dstS,
    const int* __restrict__ n2g, const float* __restrict__ Rp)
{
  __shared__ u16 AsD[2*1024];
  __shared__ u16 BsD[2*16384];
  const int t = threadIdx.x;          // 0..511
  const int bm = blockIdx.x;
  const int lane = t&63;
  const int wave = t>>6;
  const float TP = 6.283185307179586f;

  f32x4 acc[2][4];
  #pragma unroll
  for (int i=0;i<2;i++)
    #pragma unroll
    for (int j=0;j<4;j++) acc[i][j] = (f32x4){0.f,0.f,0.f,0.f};

  const int sr = t>>2;                            // B row (0..127), A row (t<128)
  const int sk = (((t&3) ^ ((t>>3)&3)))*8;        // T2 source-side logical granule
  const u16* Bg0 = B + (size_t)sr*K + sk;
  const u16* Bg1 = B + (size_t)(sr+128)*K + sk;
  const u16* Bg2 = B + (size_t)(sr+256)*K + sk;
  const u16* Bg3 = B + (size_t)(sr+384)*K + sk;

  // A source (E2 path)
  int ar = bm*32 + (t>>2); if (ar > M-1) ar = M-1;
  const u16* Ag = TRIGA ? nullptr : (A + (size_t)ar*K + sk);
  // trig params (E1 path)
  float fx0=0.f, fx1=0.f, fx2=0.f;
  if (TRIGA && t<128){
    int ge = cbase + bm*32 + (t>>2);
    fx0 = fdS[(size_t)ge*3+0]; fx1 = fdS[(size_t)ge*3+1]; fx2 = fdS[(size_t)ge*3+2];
  }

  // T2 read-side granule permutation
  const int rg = ((lane>>4) ^ ((lane>>1)&3))*8;
  const u16* ApL = &AsD[(lane&15)*32 + rg];
  const u16* BpL = &BsD[(wave*64 + (lane&15))*32 + rg];

  const int nk = K>>5;
  #define STAGE(kt, b) { \
    const int ko = (kt)*32; \
    gld16(Bg0 + ko, (u16*)BsD + (b)*16384 + t*8); \
    gld16(Bg1 + ko, (u16*)BsD + (b)*16384 + 4096 + t*8); \
    gld16(Bg2 + ko, (u16*)BsD + (b)*16384 + 8192 + t*8); \
    gld16(Bg3 + ko, (u16*)BsD + (b)*16384 + 12288 + t*8); \
    if (t < 128){ \
      if constexpr (TRIGA){ \
        int c = ko + sk; int isc = (c>=384); int cc = isc? c-384 : c; \
        int d = cc>>7; float x = (d==0)?fx0:((d==1)?fx1:fx2); \
        float fb = (float)(cc&127); float off = isc?0.25f:0.0f; \
        short8 v; \
        _Pragma("unroll") \
        for (int j=0;j<8;j++){ \
          float w = x*(fb+(float)j); w -= rintf(w); \
          v[j] = (short)f2bf(__sinf(TP*(w+off))); } \
        *(short8*)((u16*)AsD + (b)*1024 + t*8) = v; \
      } else { \
        gld16(Ag + ko, (u16*)AsD + (b)*1024 + t*8); \
      } \
    } \
  }

  STAGE(0,0)
  STAGE(1,1)
  asm volatile("s_waitcnt vmcnt(4) lgkmcnt(0)" ::: "memory");
  __builtin_amdgcn_s_barrier();

  int cur = 0;
  for (int ki=0; ki<nk; ++ki){
    short8 af[2], bf[4];
    const int ca = cur*1024, cbb = cur*16384;
    #pragma unroll
    for (int mi=0;mi<2;mi++) af[mi] = *(const short8*)(ApL + ca + mi*512);
    #pragma unroll
    for (int ni=0;ni<4;ni++) bf[ni] = *(const short8*)(BpL + cbb + ni*512);
    asm volatile("s_waitcnt lgkmcnt(0)" ::: "memory");
    __builtin_amdgcn_s_barrier();              // all waves done reading cur -> free
    if (ki+2 < nk) STAGE(ki+2, cur)
    #pragma unroll
    for (int mi=0;mi<2;mi++)
      #pragma unroll
      for (int ni=0;ni<4;ni++)
        acc[mi][ni] = __builtin_amdgcn_mfma_f32_16x16x32_bf16(af[mi], bf[ni], acc[mi][ni], 0,0,0);
    if (ki+2 < nk) { asm volatile("s_waitcnt vmcnt(4)" ::: "memory"); }
    else           { asm volatile("s_waitcnt vmcnt(0)" ::: "memory"); }
    __builtin_amdgcn_s_barrier();              // tile ki+1 ready in other buffer
    cur ^= 1;
  }
  #undef STAGE

  const int c0 = wave*64 + (lane&15);
  const int r0 = (lane>>4)<<2;

  if constexpr (EPI==1){
    float bz[4];
    #pragma unroll
    for (int ni=0;ni<4;ni++) bz[ni] = bias[c0 + ni*16];
    #pragma unroll
    for (int mi=0;mi<2;mi++)
      #pragma unroll
      for (int r=0;r<4;r++){
        int row = bm*32 + r0 + mi*16 + r;
        if (row < M){
          u16* o = Cb + (size_t)row*512 + c0;
          #pragma unroll
          for (int ni=0;ni<4;ni++) o[ni*16] = f2bf(siluf(acc[mi][ni][r]+bz[ni]));
        }
      }
  } else {
    #pragma unroll
    for (int mi=0;mi<2;mi++)
      #pragma unroll
      for (int r=0;r<4;r++){
        int row = bm*32 + r0 + mi*16 + r;
        if (row < M){
          int gs = cbase + row;
          int sn = nodS[gs], dn = dstS[gs];
          int g  = n2g[sn];
          const u16* Pp = PQ + (size_t)sn*1024 + c0;
          const u16* Qp = PQ + (size_t)dn*1024 + 512 + c0;
          const float* Rr = Rp + g*512 + c0;
          u16* o = Cb + (size_t)row*512 + c0;
          #pragma unroll
          for (int ni=0;ni<4;ni++){
            float v = acc[mi][ni][r] + bf2f(Pp[ni*16]) + bf2f(Qp[ni*16]) + Rr[ni*16];
            o[ni*16] = f2bf(siluf(v));
          }
        }
      }
  }
}

__global__ __launch_bounds__(512) void g_e1(const float* fdS, const u16* B, int M, int K,
    int cbase, u16* Cm, const u16* PQ, const int* nodS, const int* dstS,
    const int* n2g, const float* Rp){
  gemm512_core<2,true>(nullptr, fdS, B, M, K, cbase, Cm, nullptr, PQ, nodS, dstS, n2g, Rp);
}
__global__ __launch_bounds__(512) void g_e2(const u16* A, const u16* B, int M, int K,
    u16* Cb, const float* bias){
  gemm512_core<1,false>(A, nullptr, B, M, K, 0, Cb, bias, nullptr, nullptr, nullptr, nullptr, nullptr);
}

// ---------------- node GEMM (BM=64, BN=128, 256 thr) — unchanged from r7 ------
template<int EPI>
__device__ __forceinline__ void gemm_core(
    const u16* __restrict__ A, int lda,
    const u16* __restrict__ B, int ldb,
    int M, int K,
    u16* __restrict__ Cb, float* __restrict__ Cf, int ldc,
    const float* __restrict__ bias)
{
  __shared__ u16 As[3*2048];
  __shared__ u16 Bs[3*4096];
  const int t = threadIdx.x;
  const int bm = blockIdx.x, bn = blockIdx.y;
  const int lane = t&63;
  const int wave = t>>6;
  const int wm = wave>>1, wn = wave&1;

  f32x4 acc[2][4];
  #pragma unroll
  for (int i=0;i<2;i++)
    #pragma unroll
    for (int j=0;j<4;j++) acc[i][j] = (f32x4){0.f,0.f,0.f,0.f};

  const int sr = t>>2;
  const int sk = (((t&3) ^ ((t>>3)&3)))*8;
  int ar0 = bm*64 + sr; if (ar0 > M-1) ar0 = M-1;
  const u16* Ag0 = A + (size_t)ar0*lda + sk;
  const u16* Bg0 = B + (size_t)(bn*128 + sr)*ldb + sk;
  const u16* Bg1 = B + (size_t)(bn*128 + sr + 64)*ldb + sk;
  u16* As0 = &As[t*8];
  u16* Bs0 = &Bs[t*8];
  u16* Bs1 = &Bs[t*8 + 2048];

  const int rg = ((lane>>4) ^ ((lane>>1)&3))*8;
  const u16* ApL = &As[(wm*32 + (lane&15))*32 + rg];
  const u16* BpL = &Bs[(wn*64 + (lane&15))*32 + rg];

  const int nk = K>>5;
  #define STAGEN(kt, b) { const int ko=(kt)<<5; \
      gld16(Ag0+ko, As0+(b)*2048); \
      gld16(Bg0+ko, Bs0+(b)*4096); \
      gld16(Bg1+ko, Bs1+(b)*4096); }

  STAGEN(0,0)
  STAGEN(1,1)
  int cb=0, sb=2;
  for (int ki=0; ki<nk; ++ki){
    if (ki+1 < nk) asm volatile("s_waitcnt vmcnt(3)" ::: "memory");
    else           asm volatile("s_waitcnt vmcnt(0)" ::: "memory");
    __builtin_amdgcn_s_barrier();
    if (ki+2 < nk) STAGEN(ki+2, sb)
    const int ca = cb*2048, cbb = cb*4096;
    short8 af[2], bf[4];
    #pragma unroll
    for (int mi=0;mi<2;mi++) af[mi] = *(const short8*)(ApL + ca + mi*512);
    #pragma unroll
    for (int ni=0;ni<4;ni++) bf[ni] = *(const short8*)(BpL + cbb + ni*512);
    #pragma unroll
    for (int mi=0;mi<2;mi++)
      #pragma unroll
      for (int ni=0;ni<4;ni++)
        acc[mi][ni] = __builtin_amdgcn_mfma_f32_16x16x32_bf16(af[mi], bf[ni], acc[mi][ni], 0,0,0);
    cb = (cb==2)?0:cb+1;
    sb = (sb==2)?0:sb+1;
  }
  #undef STAGEN

  const int c0 = bn*128 + wn*64 + (lane&15);
  const int r0 = bm*64 + wm*32 + ((lane>>4)<<2);

  if constexpr (EPI==0){
    #pragma unroll
    for (int mi=0;mi<2;mi++)
      #pragma unroll
      for (int r=0;r<4;r++){
        int row = r0 + mi*16 + r;
        if (row < M){
          u16* o = Cb + (size_t)row*ldc + c0;
          #pragma unroll
          for (int ni=0;ni<4;ni++) o[ni*16] = f2bf(acc[mi][ni][r]);
        }
      }
  } else if constexpr (EPI==1){
    float bz[4];
    #pragma unroll
    for (int ni=0;ni<4;ni++) bz[ni] = bias[c0 + ni*16];
    #pragma unroll
    for (int mi=0;mi<2;mi++)
      #pragma unroll
      for (int r=0;r<4;r++){
        int row = r0 + mi*16 + r;
        if (row < M){
          u16* o = Cb + (size_t)row*ldc + c0;
          #pragma unroll
          for (int ni=0;ni<4;ni++) o[ni*16] = f2bf(siluf(acc[mi][ni][r]+bz[ni]));
        }
      }
  } else {
    float bz[4];
    #pragma unroll
    for (int ni=0;ni<4;ni++) bz[ni] = bias[c0 + ni*16];
    #pragma unroll
    for (int mi=0;mi<2;mi++)
      #pragma unroll
      for (int r=0;r<4;r++){
        int row = r0 + mi*16 + r;
        if (row < M){
          float* hp = Cf + (size_t)row*ldc + c0;
          #pragma unroll
          for (int ni=0;ni<4;ni++) hp[ni*16] += siluf(acc[mi][ni][r]+bz[ni]);
        }
      }
  }
}

#define GEMM_ARGS const u16* A, int lda, const u16* B, int ldb, int M, int K, \
    u16* Cb, float* Cf, int ldc, const float* bias
#define GEMM_PASS A,lda,B,ldb,M,K,Cb,Cf,ldc,bias

__global__ __launch_bounds__(256) void g_pq(GEMM_ARGS){ gemm_core<0>(GEMM_PASS); }
__global__ __launch_bounds__(256) void g_n1(GEMM_ARGS){ gemm_core<1>(GEMM_PASS); }
__global__ __launch_bounds__(256) void g_n2(GEMM_ARGS){ gemm_core<2>(GEMM_PASS); }

// ---------------- small kernels ----------------
__global__ void k_prep(const float* __restrict__ tp, const float* __restrict__ Wt,
                       const float* __restrict__ Wa, const float* __restrict__ ba,
                       float* __restrict__ bias2){
  __shared__ float te[256];
  int t=threadIdx.x;
  te[t] = tp[0]*Wt[t];
  __syncthreads();
  for (int i=t;i<512;i+=256){
    float s = ba[i];
    const float* wr = Wa + (size_t)i*768 + 512;
    for (int j=0;j<256;j++) s += wr[j]*te[j];
    bias2[i]=s;
  }
}

__global__ void k_h0(const float* __restrict__ emb, const float* __restrict__ Wa,
                     const float* __restrict__ bias2, float* __restrict__ h0){
  __shared__ float et[512];
  int ty=blockIdx.x, t=threadIdx.x;
  et[t]=emb[(size_t)ty*512+t]; et[t+256]=emb[(size_t)ty*512+t+256];
  __syncthreads();
  for (int i=t;i<512;i+=256){
    float s=bias2[i];
    const float* wr = Wa + (size_t)i*768;
    for (int k=0;k<512;k++) s += wr[k]*et[k];
    h0[(size_t)ty*512+i]=siluf(s);
  }
}

__global__ void k_inith(const int* __restrict__ at, const float* __restrict__ h0,
                        float* __restrict__ h){
  int total=TN*512;
  for (int i=blockIdx.x*blockDim.x+threadIdx.x; i<total; i+=gridDim.x*blockDim.x){
    int n=i>>9, c=i&511;
    h[i]=h0[(size_t)at[n]*512+c];
  }
}

__global__ void k_count(const int* __restrict__ src, int* __restrict__ counts){
  for (int e=blockIdx.x*blockDim.x+threadIdx.x; e<TE; e+=gridDim.x*blockDim.x)
    atomicAdd(&counts[src[e]],1);
}

__global__ void k_scan(const int* __restrict__ cnt, int* __restrict__ iptr){
  __shared__ int sums[1024];
  const int T=1024, n=TN;
  int t=threadIdx.x;
  const int chunk=(n+T-1)/T;
  int s=0;
  for (int i=0;i<chunk;i++){ int idx=t*chunk+i; if(idx<n) s+=cnt[idx]; }
  sums[t]=s; __syncthreads();
  for (int off=1; off<T; off<<=1){
    int v = (t>=off)? sums[t-off] : 0;
    __syncthreads();
    sums[t]+=v;
    __syncthreads();
  }
  int run = (t==0)?0:sums[t-1];
  for (int i=0;i<chunk;i++){
    int idx=t*chunk+i;
    if(idx<n){ iptr[idx]=run; run+=cnt[idx]; }
  }
  if (t==T-1) iptr[n]=run;
}

__global__ void k_fill(const int* __restrict__ src, const int* __restrict__ dst,
                       const float* __restrict__ fd, const int* __restrict__ iptr,
                       int* __restrict__ slots, int* __restrict__ nodS,
                       int* __restrict__ dstS, float* __restrict__ fdS){
  for (int e=blockIdx.x*blockDim.x+threadIdx.x; e<TE; e+=gridDim.x*blockDim.x){
    int s=src[e];
    int p=atomicAdd(&slots[s],1);
    int gs=iptr[s]+p;
    nodS[gs]=s; dstS[gs]=dst[e];
    fdS[(size_t)gs*3+0]=fd[(size_t)e*3+0];
    fdS[(size_t)gs*3+1]=fd[(size_t)e*3+1];
    fdS[(size_t)gs*3+2]=fd[(size_t)e*3+2];
  }
}

__global__ void k_R(const float* __restrict__ lat, const float* __restrict__ eW1,
                    const float* __restrict__ eb1, float* __restrict__ Rp){
  int total = 2*64*512;
  for (int i=blockIdx.x*blockDim.x+threadIdx.x; i<total; i+=gridDim.x*blockDim.x){
    int l = i>>15;
    int g = (i>>9)&63;
    int o = i&511;
    float s = eb1[l*512+o];
    const float* wr = eW1 + ((size_t)l*512 + o)*1798 + 1024;
    const float* lr = lat + g*6;
    #pragma unroll
    for (int k=0;k<6;k++) s += lr[k]*wr[k];
    Rp[i]=s;
  }
}

struct PackDesc { const float* src; u16* dst; int rows, cols, ld, off; };
struct PackArgs { PackDesc d[12]; };
__global__ void k_pack(PackArgs pa){
  PackDesc d = pa.d[blockIdx.y];
  int total = d.rows*d.cols;
  for (int i = blockIdx.x*blockDim.x + threadIdx.x; i<total; i += gridDim.x*blockDim.x){
    int r = i/d.cols, c = i - r*d.cols;
    d.dst[i] = f2bf(d.src[(size_t)r*d.ld + d.off + c]);
  }
}

__global__ void k_ln(const float* __restrict__ h, const float* __restrict__ g,
                     const float* __restrict__ b, u16* __restrict__ hcat){
  int row = blockIdx.x, t = threadIdx.x;
  const float* hr = h + (size_t)row*512;
  float v0 = hr[t], v1 = hr[t+256];
  float s = v0+v1, ss = v0*v0+v1*v1;
  blockReduce2(s, ss);
  float mean = s*(1.0f/512.0f);
  float var  = ss*(1.0f/512.0f) - mean*mean;
  float rs = rsqrtf(var + 1e-5f);
  u16* o = hcat + (size_t)row*1024;
  o[t]     = f2bf((v0-mean)*rs*g[t]     + b[t]);
  o[t+256] = f2bf((v1-mean)*rs*g[t+256] + b[t+256]);
}

__global__ void k_aggpart(const u16* __restrict__ xc, const int* __restrict__ iptr,
                          int s0, int s1, float* __restrict__ aggf){
  int n=blockIdx.x, t=threadIdx.x;
  int beg=iptr[n], end=iptr[n+1];
  if (beg<s0) beg=s0;
  if (end>s1) end=s1;
  if (beg>=end) return;
  float a0=0.f, a1=0.f;
  for (int i=beg;i<end;i++){
    const u16* xr = xc + (size_t)(i-s0)*512;
    a0 += bf2f(xr[t]); a1 += bf2f(xr[t+256]);
  }
  float* ar = aggf + (size_t)n*512;
  ar[t] += a0; ar[t+256] += a1;
}

__global__ void k_aggfin(const float* __restrict__ aggf, const int* __restrict__ counts,
                         u16* __restrict__ hcat){
  int n=blockIdx.x, t=threadIdx.x;
  int c=counts[n]; if (c<1) c=1;
  float inv = 1.0f/(float)c;
  const float* ar = aggf + (size_t)n*512;
  u16* o = hcat + (size_t)n*1024 + 512;
  o[t]     = f2bf(ar[t]*inv);
  o[t+256] = f2bf(ar[t+256]*inv);
}

__global__ void k_final(const float* __restrict__ h, const float* __restrict__ g,
                        const float* __restrict__ b, const float* __restrict__ Wc,
                        float* __restrict__ out){
  int row=blockIdx.x, t=threadIdx.x;
  const float* hr = h + (size_t)row*512;
  float v0=hr[t], v1=hr[t+256];
  float s=v0+v1, ss=v0*v0+v1*v1;
  blockReduce2(s,ss);
  float mean=s*(1.0f/512.0f), var=ss*(1.0f/512.0f)-mean*mean, rs=rsqrtf(var+1e-5f);
  float n0=(v0-mean)*rs*g[t]+b[t];
  float n1=(v1-mean)*rs*g[t+256]+b[t+256];
  float p0 = n0*Wc[t]      + n1*Wc[t+256];
  float p1 = n0*Wc[512+t]  + n1*Wc[512+t+256];
  float p2 = n0*Wc[1024+t] + n1*Wc[1024+t+256];
  for (int off=32; off>0; off>>=1){
    p0+=__shfl_down(p0,off,64); p1+=__shfl_down(p1,off,64); p2+=__shfl_down(p2,off,64);
  }
  __shared__ float rp[4][3];
  int lane=t&63, wave=t>>6;
  if (lane==0){ rp[wave][0]=p0; rp[wave][1]=p1; rp[wave][2]=p2; }
  __syncthreads();
  if (t<3) out[(size_t)row*3+t] = rp[0][t]+rp[1][t]+rp[2][t]+rp[3][t];
}

__global__ void k_report(float* out, int n, float val){
  for (int i=blockIdx.x*blockDim.x+threadIdx.x; i<n; i+=gridDim.x*blockDim.x) out[i]=val;
}

extern "C" void kernel_launch(void* const* d_in, const int* in_sizes, int n_in,
                              void* d_out, int out_size, void* d_ws, size_t ws_size,
                              hipStream_t stream)
{
  const int*   atom  = (const int*)  d_in[0];
  const int*   n2g   = (const int*)  d_in[1];
  const int*   eidx  = (const int*)  d_in[2];
  const float* fdiff = (const float*)d_in[3];
  const float* lat   = (const float*)d_in[4];
  const float* tp    = (const float*)d_in[5];
  const float* emb   = (const float*)d_in[6];
  const float* Wt    = (const float*)d_in[7];
  const float* Wa    = (const float*)d_in[8];
  const float* ba    = (const float*)d_in[9];
  const float* lng   = (const float*)d_in[10];
  const float* lnb   = (const float*)d_in[11];
  const float* eW1   = (const float*)d_in[12];
  const float* eb1   = (const float*)d_in[13];
  const float* eW2   = (const float*)d_in[14];
  const float* eb2   = (const float*)d_in[15];
  const float* nW1   = (const float*)d_in[16];
  const float* nb1   = (const float*)d_in[17];
  const float* nW2   = (const float*)d_in[18];
  const float* nb2   = (const float*)d_in[19];
  const float* flng  = (const float*)d_in[20];
  const float* flnb  = (const float*)d_in[21];
  const float* Wc    = (const float*)d_in[22];
  float* out = (float*)d_out;

  char* ws = (char*)d_ws;
  if (ws_size < WS_NEED){
    k_report<<<64,256,0,stream>>>(out, out_size, (float)(ws_size>>20));
    return;
  }

  float* h    = (float*)(ws+OFF_H);
  u16*   PQ   = (u16*)(ws+OFF_PQ);
  u16*   hcat = (u16*)(ws+OFF_HCAT);
  float* aggf = (float*)(ws+OFF_AGGF);
  u16*   m_c  = (u16*)(ws+OFF_MC);
  u16*   u    = (u16*)(ws+OFF_MC);
  u16*   x_c  = (u16*)(ws+OFF_XD);
  u16*   Wab  = (u16*)(ws+OFF_WAB);
  u16*   W1d  = (u16*)(ws+OFF_W1D);
  u16*   W2c  = (u16*)(ws+OFF_W2);
  u16*   Wn1  = (u16*)(ws+OFF_WN1);
  u16*   Wn2  = (u16*)(ws+OFF_WN2);
  float* Rp   = (float*)(ws+OFF_RP);
  float* h0   = (float*)(ws+OFF_H0);
  float* b2   = (float*)(ws+OFF_B2);
  int* counts = (int*)(ws+OFF_CNT);
  int* slots  = (int*)(ws+OFF_SLOT);
  int* iptr   = (int*)(ws+OFF_IPTR);
  int* nodS   = (int*)(ws+OFF_NOD);
  int* dstS   = (int*)(ws+OFF_DST);
  float* fdS  = (float*)(ws+OFF_FDS);
  const int* src = eidx;
  const int* dst = eidx + TE;

  hipMemsetAsync(ws+OFF_CNT, 0, OFF_SLOT + (size_t)TN*4 - OFF_CNT, stream);

  k_prep<<<1,256,0,stream>>>(tp, Wt, Wa, ba, b2);
  k_h0<<<119,256,0,stream>>>(emb, Wa, b2, h0);
  k_inith<<<1024,256,0,stream>>>(atom, h0, h);
  k_count<<<391,256,0,stream>>>(src, counts);
  k_scan<<<1,1024,0,stream>>>(counts, iptr);
  k_fill<<<391,256,0,stream>>>(src, dst, fdiff, iptr, slots, nodS, dstS, fdS);
  k_R<<<256,256,0,stream>>>(lat, eW1, eb1, Rp);

  PackArgs pa;
  for (int l=0;l<2;l++){
    const float* e1 = eW1 + (size_t)l*512*1798;
    pa.d[l*6+0] = {e1, Wab + (size_t)l*1024*512,             512, 512, 1798, 0};
    pa.d[l*6+1] = {e1, Wab + (size_t)l*1024*512 + 512*512,   512, 512, 1798, 512};
    pa.d[l*6+2] = {e1, W1d + (size_t)l*512*768,              512, 768, 1798, 1030};
    pa.d[l*6+3] = {eW2 + (size_t)l*512*512, W2c + (size_t)l*512*512, 512, 512, 512, 0};
    pa.d[l*6+4] = {nW1 + (size_t)l*512*1024, Wn1 + (size_t)l*512*1024, 512, 1024, 1024, 0};
    pa.d[l*6+5] = {nW2 + (size_t)l*512*512, Wn2 + (size_t)l*512*512, 512, 512, 512, 0};
  }
  k_pack<<<dim3(128,12),256,0,stream>>>(pa);

  const int BME32 = (EC+31)/32;   // 782
  const int BMN   = (TN+63)/64;   // 157
  for (int l=0;l<2;l++){
    k_ln<<<TN,256,0,stream>>>(h, lng+(size_t)l*512, lnb+(size_t)l*512, hcat);
    g_pq<<<dim3(BMN,8),256,0,stream>>>(hcat, 1024, Wab+(size_t)l*1024*512, 512,
        TN, 512, PQ, nullptr, 1024, nullptr);
    hipMemsetAsync(aggf, 0, (size_t)TN*512*4, stream);
    for (int c=0;c<NCH;c++){
      int s0 = c*EC;
      g_e1<<<BME32,512,0,stream>>>(fdS, W1d+(size_t)l*512*768, EC, 768,
          s0, m_c, PQ, nodS, dstS, n2g, Rp+(size_t)l*64*512);
      g_e2<<<BME32,512,0,stream>>>(m_c, W2c+(size_t)l*512*512, EC, 512,
          x_c, eb2+(size_t)l*512);
      k_aggpart<<<TN,256,0,stream>>>(x_c, iptr, s0, s0+EC, aggf);
    }
    k_aggfin<<<TN,256,0,stream>>>(aggf, counts, hcat);
    g_n1<<<dim3(BMN,4),256,0,stream>>>(hcat, 1024, Wn1+(size_t)l*512*1024, 1024,
        TN, 1024, u, nullptr, 512, nb1+(size_t)l*512);
    g_n2<<<dim3(BMN,4),256,0,stream>>>(u, 512, Wn2+(size_t)l*512*512, 512,
        TN, 512, nullptr, h, 512, nb2+(size_t)l*512);
  }
  k_final<<<TN,256,0,stream>>>(h, flng, flnb, Wc, out);
}

// Round 10
// 1220.273 us; speedup vs baseline: 1.1725x; 1.1725x over previous
//
#include <hip/hip_runtime.h>
#include <stdint.h>

typedef unsigned short u16;
typedef unsigned int u32;
typedef __attribute__((ext_vector_type(8))) short short8;
typedef __attribute__((ext_vector_type(4))) float f32x4;

#define TN 10000
#define TE 100000
#define PAD 128

static constexpr size_t A256(size_t x){ return (x+255)/256*256; }

__device__ __forceinline__ float bf2f(u16 u){ u32 x=((u32)u)<<16; float f; __builtin_memcpy(&f,&x,4); return f; }
__device__ __forceinline__ u16 f2bf(float f){ u32 x; __builtin_memcpy(&x,&f,4); x = x + 0x7fffu + ((x>>16)&1u); return (u16)(x>>16); }
__device__ __forceinline__ float siluf(float v){ return v*(1.0f/(1.0f+__expf(-v))); }

__device__ __forceinline__ void gld16(const void* g, void* l){
  __builtin_amdgcn_global_load_lds((const __attribute__((address_space(1))) u32*)g,
                                   (__attribute__((address_space(3))) u32*)l, 16, 0, 0);
}

__device__ __forceinline__ void blockReduce2(float& s, float& ss){
  for (int off=32; off>0; off>>=1){ s += __shfl_down(s,off,64); ss += __shfl_down(ss,off,64); }
  __shared__ float red[8];
  int lane = threadIdx.x&63, wave = threadIdx.x>>6;
  if (lane==0){ red[wave*2]=s; red[wave*2+1]=ss; }
  __syncthreads();
  s  = red[0]+red[2]+red[4]+red[6];
  ss = red[1]+red[3]+red[5]+red[7];
}

// ---------------- GEMM core (r7 winner): BM=64 x BN=128, 256 thr, 3-deep -----
// counted vmcnt(3), one barrier/step, T2 K-granule XOR swizzle both-sides.
// SWZ: 1D grid with XCD-chunked bijective remap (bn 4-wide).
// EPI 0: bf16 store. 1: silu(acc+bias)->bf16.
// 2: edge epilogue silu(acc + P[src] + Q[dst] + R[graph]) (cbase = chunk offset)
// 3: residual f32: h += silu(acc+bias)
template<int EPI, bool SWZ>
__device__ __forceinline__ void gemm_core(
    const u16* __restrict__ A, int lda,
    const u16* __restrict__ B, int ldb,
    int M, int K,
    u16* __restrict__ Cb, float* __restrict__ Cf, int ldc,
    const float* __restrict__ bias,
    int cbase,
    const u16* __restrict__ PQ,
    const int* __restrict__ nodS, const int* __restrict__ dstS,
    const int* __restrict__ n2g, const float* __restrict__ Rp,
    int nwg)
{
  __shared__ u16 As[3*2048];
  __shared__ u16 Bs[3*4096];
  int bm, bn;
  if constexpr (SWZ){
    int orig = blockIdx.x;
    int q = nwg>>3, r = nwg&7;
    int xcd = orig&7, idx = orig>>3;
    int wg = (xcd<r ? xcd*(q+1) : r*(q+1)+(xcd-r)*q) + idx;   // m204 bijective
    bm = wg>>2; bn = wg&3;
  } else { bm = blockIdx.x; bn = blockIdx.y; }
  const int t = threadIdx.x;
  const int lane = t&63;
  const int wave = t>>6;
  const int wm = wave>>1, wn = wave&1;

  f32x4 acc[2][4];
  #pragma unroll
  for (int i=0;i<2;i++)
    #pragma unroll
    for (int j=0;j<4;j++) acc[i][j] = (f32x4){0.f,0.f,0.f,0.f};

  const int sr = t>>2;
  const int sk = (((t&3) ^ ((t>>3)&3)))*8;
  int ar0 = bm*64 + sr; if (ar0 > M-1) ar0 = M-1;
  const u16* Ag0 = A + (size_t)ar0*lda + sk;
  const u16* Bg0 = B + (size_t)(bn*128 + sr)*ldb + sk;
  const u16* Bg1 = B + (size_t)(bn*128 + sr + 64)*ldb + sk;
  u16* As0 = &As[t*8];
  u16* Bs0 = &Bs[t*8];
  u16* Bs1 = &Bs[t*8 + 2048];

  const int rg = ((lane>>4) ^ ((lane>>1)&3))*8;
  const u16* ApL = &As[(wm*32 + (lane&15))*32 + rg];
  const u16* BpL = &Bs[(wn*64 + (lane&15))*32 + rg];

  const int nk = K>>5;
  #define STAGEN(kt, b) { const int ko=(kt)<<5; \
      gld16(Ag0+ko, As0+(b)*2048); \
      gld16(Bg0+ko, Bs0+(b)*4096); \
      gld16(Bg1+ko, Bs1+(b)*4096); }

  STAGEN(0,0)
  STAGEN(1,1)
  int cb=0, sb=2;
  for (int ki=0; ki<nk; ++ki){
    if (ki+1 < nk) asm volatile("s_waitcnt vmcnt(3)" ::: "memory");
    else           asm volatile("s_waitcnt vmcnt(0)" ::: "memory");
    __builtin_amdgcn_s_barrier();
    if (ki+2 < nk) STAGEN(ki+2, sb)
    const int ca = cb*2048, cbb = cb*4096;
    short8 af[2], bf[4];
    #pragma unroll
    for (int mi=0;mi<2;mi++) af[mi] = *(const short8*)(ApL + ca + mi*512);
    #pragma unroll
    for (int ni=0;ni<4;ni++) bf[ni] = *(const short8*)(BpL + cbb + ni*512);
    #pragma unroll
    for (int mi=0;mi<2;mi++)
      #pragma unroll
      for (int ni=0;ni<4;ni++)
        acc[mi][ni] = __builtin_amdgcn_mfma_f32_16x16x32_bf16(af[mi], bf[ni], acc[mi][ni], 0,0,0);
    cb = (cb==2)?0:cb+1;
    sb = (sb==2)?0:sb+1;
  }
  #undef STAGEN

  const int c0 = bn*128 + wn*64 + (lane&15);
  const int r0 = bm*64 + wm*32 + ((lane>>4)<<2);

  if constexpr (EPI==0){
    #pragma unroll
    for (int mi=0;mi<2;mi++)
      #pragma unroll
      for (int r=0;r<4;r++){
        int row = r0 + mi*16 + r;
        if (row < M){
          u16* o = Cb + (size_t)row*ldc + c0;
          #pragma unroll
          for (int ni=0;ni<4;ni++) o[ni*16] = f2bf(acc[mi][ni][r]);
        }
      }
  } else if constexpr (EPI==1){
    float bz[4];
    #pragma unroll
    for (int ni=0;ni<4;ni++) bz[ni] = bias[c0 + ni*16];
    #pragma unroll
    for (int mi=0;mi<2;mi++)
      #pragma unroll
      for (int r=0;r<4;r++){
        int row = r0 + mi*16 + r;
        if (row < M){
          u16* o = Cb + (size_t)row*ldc + c0;
          #pragma unroll
          for (int ni=0;ni<4;ni++) o[ni*16] = f2bf(siluf(acc[mi][ni][r]+bz[ni]));
        }
      }
  } else if constexpr (EPI==2){
    #pragma unroll
    for (int mi=0;mi<2;mi++)
      #pragma unroll
      for (int r=0;r<4;r++){
        int row = r0 + mi*16 + r;
        if (row < M){
          int gs = cbase + row;
          int sn = nodS[gs], dn = dstS[gs];
          int g  = n2g[sn];
          const u16* Pp = PQ + (size_t)sn*1024 + c0;
          const u16* Qp = PQ + (size_t)dn*1024 + 512 + c0;
          const float* Rr = Rp + g*512 + c0;
          u16* o = Cb + (size_t)row*ldc + c0;
          #pragma unroll
          for (int ni=0;ni<4;ni++){
            float v = acc[mi][ni][r] + bf2f(Pp[ni*16]) + bf2f(Qp[ni*16]) + Rr[ni*16];
            o[ni*16] = f2bf(siluf(v));
          }
        }
      }
  } else {
    float bz[4];
    #pragma unroll
    for (int ni=0;ni<4;ni++) bz[ni] = bias[c0 + ni*16];
    #pragma unroll
    for (int mi=0;mi<2;mi++)
      #pragma unroll
      for (int r=0;r<4;r++){
        int row = r0 + mi*16 + r;
        if (row < M){
          float* hp = Cf + (size_t)row*ldc + c0;
          #pragma unroll
          for (int ni=0;ni<4;ni++) hp[ni*16] += siluf(acc[mi][ni][r]+bz[ni]);
        }
      }
  }
}

#define GEMM_ARGS const u16* A, int lda, const u16* B, int ldb, int M, int K, \
    u16* Cb, float* Cf, int ldc, const float* bias, int cbase, const u16* PQ, \
    const int* nodS, const int* dstS, const int* n2g, const float* Rp, int nwg
#define GEMM_PASS A,lda,B,ldb,M,K,Cb,Cf,ldc,bias,cbase,PQ,nodS,dstS,n2g,Rp,nwg

__global__ __launch_bounds__(256) void g_pq(GEMM_ARGS){ gemm_core<0,false>(GEMM_PASS); }
__global__ __launch_bounds__(256) void g_n1(GEMM_ARGS){ gemm_core<1,false>(GEMM_PASS); }
__global__ __launch_bounds__(256) void g_n2(GEMM_ARGS){ gemm_core<3,false>(GEMM_PASS); }
__global__ __launch_bounds__(256) void g_e1(GEMM_ARGS){ gemm_core<2,true>(GEMM_PASS); }
__global__ __launch_bounds__(256) void g_e2(GEMM_ARGS){ gemm_core<1,true>(GEMM_PASS); }

// ---- demb: sin/cos(2pi x f) via angle-addition recurrence (2 sincos + 28 FMA / 8 out)
__global__ void k_demb(const float* __restrict__ fdS, int cbase, int M,
                       u16* __restrict__ dembC){
  const float TP = 6.283185307179586f;
  int total = M*96;
  for (int i = blockIdx.x*blockDim.x+threadIdx.x; i<total; i+=gridDim.x*blockDim.x){
    int row = i/96;
    int g   = i - row*96;
    int col = g*8;
    int isc = col>=384;
    int cc = isc ? col-384 : col;
    int d = cc>>7;
    float x = fdS[(size_t)(cbase+row)*3 + d];
    float fb = (float)(cc&127);
    float w0 = x*fb; w0 -= rintf(w0);
    float s, c, ds, dc;
    __sincosf(TP*w0, &s, &c);
    __sincosf(TP*x, &ds, &dc);
    short8 v;
    #pragma unroll
    for (int j=0;j<8;j++){
      v[j] = (short)f2bf(isc ? c : s);
      float s2 = s*dc + c*ds;
      float c2 = c*dc - s*ds;
      s = s2; c = c2;
    }
    *(short8*)(dembC + (size_t)row*768 + col) = v;
  }
}

// ---------------- small kernels ----------------
__global__ void k_prep(const float* __restrict__ tp, const float* __restrict__ Wt,
                       const float* __restrict__ Wa, const float* __restrict__ ba,
                       float* __restrict__ bias2){
  __shared__ float te[256];
  int t=threadIdx.x;
  te[t] = tp[0]*Wt[t];
  __syncthreads();
  for (int i=t;i<512;i+=256){
    float s = ba[i];
    const float* wr = Wa + (size_t)i*768 + 512;
    for (int j=0;j<256;j++) s += wr[j]*te[j];
    bias2[i]=s;
  }
}

__global__ void k_h0(const float* __restrict__ emb, const float* __restrict__ Wa,
                     const float* __restrict__ bias2, float* __restrict__ h0){
  __shared__ float et[512];
  int ty=blockIdx.x, t=threadIdx.x;
  et[t]=emb[(size_t)ty*512+t]; et[t+256]=emb[(size_t)ty*512+t+256];
  __syncthreads();
  for (int i=t;i<512;i+=256){
    float s=bias2[i];
    const float* wr = Wa + (size_t)i*768;
    for (int k=0;k<512;k++) s += wr[k]*et[k];
    h0[(size_t)ty*512+i]=siluf(s);
  }
}

__global__ void k_inith(const int* __restrict__ at, const float* __restrict__ h0,
                        float* __restrict__ h){
  int total=TN*512;
  for (int i=blockIdx.x*blockDim.x+threadIdx.x; i<total; i+=gridDim.x*blockDim.x){
    int n=i>>9, c=i&511;
    h[i]=h0[(size_t)at[n]*512+c];
  }
}

__global__ void k_count(const int* __restrict__ src, int* __restrict__ counts){
  for (int e=blockIdx.x*blockDim.x+threadIdx.x; e<TE; e+=gridDim.x*blockDim.x)
    atomicAdd(&counts[src[e]],1);
}

__global__ void k_scan(const int* __restrict__ cnt, int* __restrict__ iptr){
  __shared__ int sums[1024];
  const int T=1024, n=TN;
  int t=threadIdx.x;
  const int chunk=(n+T-1)/T;
  int s=0;
  for (int i=0;i<chunk;i++){ int idx=t*chunk+i; if(idx<n) s+=cnt[idx]; }
  sums[t]=s; __syncthreads();
  for (int off=1; off<T; off<<=1){
    int v = (t>=off)? sums[t-off] : 0;
    __syncthreads();
    sums[t]+=v;
    __syncthreads();
  }
  int run = (t==0)?0:sums[t-1];
  for (int i=0;i<chunk;i++){
    int idx=t*chunk+i;
    if(idx<n){ iptr[idx]=run; run+=cnt[idx]; }
  }
  if (t==T-1) iptr[n]=run;
}

__global__ void k_fill(const int* __restrict__ src, const int* __restrict__ dst,
                       const float* __restrict__ fd, const int* __restrict__ iptr,
                       int* __restrict__ slots, int* __restrict__ nodS,
                       int* __restrict__ dstS, float* __restrict__ fdS){
  for (int e=blockIdx.x*blockDim.x+threadIdx.x; e<TE; e+=gridDim.x*blockDim.x){
    int s=src[e];
    int p=atomicAdd(&slots[s],1);
    int gs=iptr[s]+p;
    nodS[gs]=s; dstS[gs]=dst[e];
    fdS[(size_t)gs*3+0]=fd[(size_t)e*3+0];
    fdS[(size_t)gs*3+1]=fd[(size_t)e*3+1];
    fdS[(size_t)gs*3+2]=fd[(size_t)e*3+2];
  }
}

__global__ void k_R(const float* __restrict__ lat, const float* __restrict__ eW1,
                    const float* __restrict__ eb1, float* __restrict__ Rp){
  int total = 2*64*512;
  for (int i=blockIdx.x*blockDim.x+threadIdx.x; i<total; i+=gridDim.x*blockDim.x){
    int l = i>>15;
    int g = (i>>9)&63;
    int o = i&511;
    float s = eb1[l*512+o];
    const float* wr = eW1 + ((size_t)l*512 + o)*1798 + 1024;
    const float* lr = lat + g*6;
    #pragma unroll
    for (int k=0;k<6;k++) s += lr[k]*wr[k];
    Rp[i]=s;
  }
}

struct PackDesc { const float* src; u16* dst; int rows, cols, ld, off; };
struct PackArgs { PackDesc d[12]; };
__global__ void k_pack(PackArgs pa){
  PackDesc d = pa.d[blockIdx.y];
  int total = d.rows*d.cols;
  for (int i = blockIdx.x*blockDim.x + threadIdx.x; i<total; i += gridDim.x*blockDim.x){
    int r = i/d.cols, c = i - r*d.cols;
    d.dst[i] = f2bf(d.src[(size_t)r*d.ld + d.off + c]);
  }
}

__global__ void k_ln(const float* __restrict__ h, const float* __restrict__ g,
                     const float* __restrict__ b, u16* __restrict__ hcat){
  int row = blockIdx.x, t = threadIdx.x;
  const float* hr = h + (size_t)row*512;
  float v0 = hr[t], v1 = hr[t+256];
  float s = v0+v1, ss = v0*v0+v1*v1;
  blockReduce2(s, ss);
  float mean = s*(1.0f/512.0f);
  float var  = ss*(1.0f/512.0f) - mean*mean;
  float rs = rsqrtf(var + 1e-5f);
  u16* o = hcat + (size_t)row*1024;
  o[t]     = f2bf((v0-mean)*rs*g[t]     + b[t]);
  o[t+256] = f2bf((v1-mean)*rs*g[t+256] + b[t+256]);
}

__global__ void k_aggpart(const u16* __restrict__ xc, const int* __restrict__ iptr,
                          int s0, int s1, float* __restrict__ aggf){
  int n=blockIdx.x, t=threadIdx.x;
  int beg=iptr[n], end=iptr[n+1];
  if (beg<s0) beg=s0;
  if (end>s1) end=s1;
  if (beg>=end) return;
  float a0=0.f, a1=0.f;
  for (int i=beg;i<end;i++){
    const u16* xr = xc + (size_t)(i-s0)*512;
    a0 += bf2f(xr[t]); a1 += bf2f(xr[t+256]);
  }
  float* ar = aggf + (size_t)n*512;
  ar[t] += a0; ar[t+256] += a1;
}

__global__ void k_aggfin(const float* __restrict__ aggf, const int* __restrict__ counts,
                         u16* __restrict__ hcat){
  int n=blockIdx.x, t=threadIdx.x;
  int c=counts[n]; if (c<1) c=1;
  float inv = 1.0f/(float)c;
  const float* ar = aggf + (size_t)n*512;
  u16* o = hcat + (size_t)n*1024 + 512;
  o[t]     = f2bf(ar[t]*inv);
  o[t+256] = f2bf(ar[t+256]*inv);
}

// fused aggregation (NCH==1): CSR sum over x rows, normalize, write hcat[512:]
__global__ void k_agg(const u16* __restrict__ x, const int* __restrict__ iptr,
                      u16* __restrict__ hcat){
  int n=blockIdx.x, t=threadIdx.x;
  int beg=iptr[n], end=iptr[n+1];
  float a0=0.f, a1=0.f;
  for (int i=beg;i<end;i++){
    const u16* xr = x + (size_t)i*512;
    a0 += bf2f(xr[t]); a1 += bf2f(xr[t+256]);
  }
  int c=end-beg; if (c<1) c=1;
  float inv = 1.0f/(float)c;
  u16* o = hcat + (size_t)n*1024 + 512;
  o[t]     = f2bf(a0*inv);
  o[t+256] = f2bf(a1*inv);
}

__global__ void k_final(const float* __restrict__ h, const float* __restrict__ g,
                        const float* __restrict__ b, const float* __restrict__ Wc,
                        float* __restrict__ out){
  int row=blockIdx.x, t=threadIdx.x;
  const float* hr = h + (size_t)row*512;
  float v0=hr[t], v1=hr[t+256];
  float s=v0+v1, ss=v0*v0+v1*v1;
  blockReduce2(s,ss);
  float mean=s*(1.0f/512.0f), var=ss*(1.0f/512.0f)-mean*mean, rs=rsqrtf(var+1e-5f);
  float n0=(v0-mean)*rs*g[t]+b[t];
  float n1=(v1-mean)*rs*g[t+256]+b[t+256];
  float p0 = n0*Wc[t]      + n1*Wc[t+256];
  float p1 = n0*Wc[512+t]  + n1*Wc[512+t+256];
  float p2 = n0*Wc[1024+t] + n1*Wc[1024+t+256];
  for (int off=32; off>0; off>>=1){
    p0+=__shfl_down(p0,off,64); p1+=__shfl_down(p1,off,64); p2+=__shfl_down(p2,off,64);
  }
  __shared__ float rp[4][3];
  int lane=t&63, wave=t>>6;
  if (lane==0){ rp[wave][0]=p0; rp[wave][1]=p1; rp[wave][2]=p2; }
  __syncthreads();
  if (t<3) out[(size_t)row*3+t] = rp[0][t]+rp[1][t]+rp[2][t]+rp[3][t];
}

__global__ void k_report(float* out, int n, float val){
  for (int i=blockIdx.x*blockDim.x+threadIdx.x; i<n; i+=gridDim.x*blockDim.x) out[i]=val;
}

extern "C" void kernel_launch(void* const* d_in, const int* in_sizes, int n_in,
                              void* d_out, int out_size, void* d_ws, size_t ws_size,
                              hipStream_t stream)
{
  const int*   atom  = (const int*)  d_in[0];
  const int*   n2g   = (const int*)  d_in[1];
  const int*   eidx  = (const int*)  d_in[2];
  const float* fdiff = (const float*)d_in[3];
  const float* lat   = (const float*)d_in[4];
  const float* tp    = (const float*)d_in[5];
  const float* emb   = (const float*)d_in[6];
  const float* Wt    = (const float*)d_in[7];
  const float* Wa    = (const float*)d_in[8];
  const float* ba    = (const float*)d_in[9];
  const float* lng   = (const float*)d_in[10];
  const float* lnb   = (const float*)d_in[11];
  const float* eW1   = (const float*)d_in[12];
  const float* eb1   = (const float*)d_in[13];
  const float* eW2   = (const float*)d_in[14];
  const float* eb2   = (const float*)d_in[15];
  const float* nW1   = (const float*)d_in[16];
  const float* nb1   = (const float*)d_in[17];
  const float* nW2   = (const float*)d_in[18];
  const float* nb2   = (const float*)d_in[19];
  const float* flng  = (const float*)d_in[20];
  const float* flnb  = (const float*)d_in[21];
  const float* Wc    = (const float*)d_in[22];
  float* out = (float*)d_out;

  // ---- runtime-adaptive workspace layout ----
  size_t o = 0;
  auto al = [&](size_t b){ size_t r = o; o = A256(o + b); return r; };
  size_t OH   = al((size_t)TN*512*4);
  size_t OPQ  = al((size_t)TN*1024*2);
  size_t OHC  = al((size_t)TN*1024*2);
  size_t OWAB = al((size_t)2*1024*512*2);
  size_t OW1D = al((size_t)2*512*768*2);
  size_t OW2  = al((size_t)2*512*512*2);
  size_t OWN1 = al((size_t)2*512*1024*2);
  size_t OWN2 = al((size_t)2*512*512*2);
  size_t ORP  = al((size_t)2*64*512*4);
  size_t OH0  = al((size_t)119*512*4);
  size_t OB2  = al(512*4);
  size_t OCNT = al((size_t)TN*4);
  size_t OSLOT= al((size_t)TN*4);
  size_t OIPTR= al((size_t)(TN+1)*4);
  size_t ONOD = al((size_t)(TE+PAD)*4);
  size_t ODST = al((size_t)(TE+PAD)*4);
  size_t OFDS = al((size_t)(TE+PAD)*3*4);
  size_t statEnd = o;

  int nch = 0; int ec = 0;
  size_t OAGG=0, OM=0, OX=0, ODB=0;
  const int cands[4] = {1,2,4,8};
  for (int ci=0; ci<4; ++ci){
    int c = cands[ci];
    o = statEnd;
    size_t e = TE/c;
    size_t ag = (c>1) ? al((size_t)TN*512*4) : 0;
    size_t om = al((e+PAD)*512*2);
    size_t ox = al((e+PAD)*512*2);     // E2 output: SEPARATE buffer (no in-place race)
    size_t od = al((e+PAD)*768*2);
    if (o <= ws_size){ nch=c; ec=(int)e; OAGG=ag; OM=om; OX=ox; ODB=od; break; }
  }
  char* ws = (char*)d_ws;
  if (!nch){ k_report<<<64,256,0,stream>>>(out, out_size, (float)(ws_size>>20)); return; }

  float* h    = (float*)(ws+OH);
  u16*   PQ   = (u16*)(ws+OPQ);
  u16*   hcat = (u16*)(ws+OHC);
  float* aggf = (float*)(ws+OAGG);
  u16*   m    = (u16*)(ws+OM);
  u16*   u    = (u16*)(ws+OM);        // overlay: u used only after E2 consumed m
  u16*   x    = (u16*)(ws+OX);
  u16*   demb = (u16*)(ws+ODB);
  u16*   Wab  = (u16*)(ws+OWAB);
  u16*   W1d  = (u16*)(ws+OW1D);
  u16*   W2c  = (u16*)(ws+OW2);
  u16*   Wn1  = (u16*)(ws+OWN1);
  u16*   Wn2  = (u16*)(ws+OWN2);
  float* Rp   = (float*)(ws+ORP);
  float* h0   = (float*)(ws+OH0);
  float* b2   = (float*)(ws+OB2);
  int* counts = (int*)(ws+OCNT);
  int* slots  = (int*)(ws+OSLOT);
  int* iptr   = (int*)(ws+OIPTR);
  int* nodS   = (int*)(ws+ONOD);
  int* dstS   = (int*)(ws+ODST);
  float* fdS  = (float*)(ws+OFDS);
  const int* src = eidx;
  const int* dst = eidx + TE;

  hipMemsetAsync(ws+OCNT, 0, OIPTR - OCNT, stream);

  k_prep<<<1,256,0,stream>>>(tp, Wt, Wa, ba, b2);
  k_h0<<<119,256,0,stream>>>(emb, Wa, b2, h0);
  k_inith<<<1024,256,0,stream>>>(atom, h0, h);
  k_count<<<391,256,0,stream>>>(src, counts);
  k_scan<<<1,1024,0,stream>>>(counts, iptr);
  k_fill<<<391,256,0,stream>>>(src, dst, fdiff, iptr, slots, nodS, dstS, fdS);
  k_R<<<256,256,0,stream>>>(lat, eW1, eb1, Rp);

  PackArgs pa;
  for (int l=0;l<2;l++){
    const float* e1 = eW1 + (size_t)l*512*1798;
    pa.d[l*6+0] = {e1, Wab + (size_t)l*1024*512,             512, 512, 1798, 0};
    pa.d[l*6+1] = {e1, Wab + (size_t)l*1024*512 + 512*512,   512, 512, 1798, 512};
    pa.d[l*6+2] = {e1, W1d + (size_t)l*512*768,              512, 768, 1798, 1030};
    pa.d[l*6+3] = {eW2 + (size_t)l*512*512, W2c + (size_t)l*512*512, 512, 512, 512, 0};
    pa.d[l*6+4] = {nW1 + (size_t)l*512*1024, Wn1 + (size_t)l*512*1024, 512, 1024, 1024, 0};
    pa.d[l*6+5] = {nW2 + (size_t)l*512*512, Wn2 + (size_t)l*512*512, 512, 512, 512, 0};
  }
  k_pack<<<dim3(128,12),256,0,stream>>>(pa);

  const int nbmE = (ec+63)/64;
  const int nwgE = nbmE*4;
  const int BMN  = (TN+63)/64;
  const int N0 = 0;

  if (nch==1)
    k_demb<<<4096,256,0,stream>>>(fdS, 0, TE, demb);   // frac_diff is layer-invariant

  for (int l=0;l<2;l++){
    k_ln<<<TN,256,0,stream>>>(h, lng+(size_t)l*512, lnb+(size_t)l*512, hcat);
    g_pq<<<dim3(BMN,8),256,0,stream>>>(hcat, 1024, Wab+(size_t)l*1024*512, 512,
        TN, 512, PQ, nullptr, 1024, nullptr, N0, nullptr, nullptr, nullptr, nullptr, nullptr, 0);
    if (nch>1) hipMemsetAsync(aggf, 0, (size_t)TN*512*4, stream);
    for (int c=0;c<nch;c++){
      int s0 = c*ec;
      if (nch>1) k_demb<<<2048,256,0,stream>>>(fdS, s0, ec, demb);
      g_e1<<<nwgE,256,0,stream>>>(demb, 768, W1d+(size_t)l*512*768, 768,
          ec, 768, m, nullptr, 512, nullptr,
          s0, PQ, nodS, dstS, n2g, Rp+(size_t)l*64*512, nwgE);
      g_e2<<<nwgE,256,0,stream>>>(m, 512, W2c+(size_t)l*512*512, 512,
          ec, 512, x, nullptr, 512, eb2+(size_t)l*512,
          N0, nullptr, nullptr, nullptr, nullptr, nullptr, nwgE);
      if (nch>1) k_aggpart<<<TN,256,0,stream>>>(x, iptr, s0, s0+ec, aggf);
    }
    if (nch==1) k_agg<<<TN,256,0,stream>>>(x, iptr, hcat);
    else        k_aggfin<<<TN,256,0,stream>>>(aggf, counts, hcat);
    g_n1<<<dim3(BMN,4),256,0,stream>>>(hcat, 1024, Wn1+(size_t)l*512*1024, 1024,
        TN, 1024, u, nullptr, 512, nb1+(size_t)l*512,
        N0, nullptr, nullptr, nullptr, nullptr, nullptr, 0);
    g_n2<<<dim3(BMN,4),256,0,stream>>>(u, 512, Wn2+(size_t)l*512*512, 512,
        TN, 512, nullptr, h, 512, nb2+(size_t)l*512,
        N0, nullptr, nullptr, nullptr, nullptr, nullptr, 0);
  }
  k_final<<<TN,256,0,stream>>>(h, flng, flnb, Wc, out);
}

// Round 11
// 1112.728 us; speedup vs baseline: 1.2858x; 1.0966x over previous
//
#include <hip/hip_runtime.h>
#include <stdint.h>

typedef unsigned short u16;
typedef unsigned int u32;
typedef __attribute__((ext_vector_type(8))) short short8;
typedef __attribute__((ext_vector_type(4))) float f32x4;

#define TN 10000
#define TE 100000
#define PAD 128

static constexpr size_t A256(size_t x){ return (x+255)/256*256; }

__device__ __forceinline__ float bf2f(u16 u){ u32 x=((u32)u)<<16; float f; __builtin_memcpy(&f,&x,4); return f; }
__device__ __forceinline__ u16 f2bf(float f){ u32 x; __builtin_memcpy(&x,&f,4); x = x + 0x7fffu + ((x>>16)&1u); return (u16)(x>>16); }
__device__ __forceinline__ float siluf(float v){ return v*(1.0f/(1.0f+__expf(-v))); }

__device__ __forceinline__ void gld16(const void* g, void* l){
  __builtin_amdgcn_global_load_lds((const __attribute__((address_space(1))) u32*)g,
                                   (__attribute__((address_space(3))) u32*)l, 16, 0, 0);
}

__device__ __forceinline__ void blockReduce2(float& s, float& ss){
  for (int off=32; off>0; off>>=1){ s += __shfl_down(s,off,64); ss += __shfl_down(ss,off,64); }
  __shared__ float red[8];
  int lane = threadIdx.x&63, wave = threadIdx.x>>6;
  if (lane==0){ red[wave*2]=s; red[wave*2+1]=ss; }
  __syncthreads();
  s  = red[0]+red[2]+red[4]+red[6];
  ss = red[1]+red[3]+red[5]+red[7];
}

// ---------------- GEMM core: BM=64 x BN=128, 256 thr, DEPTH-3 (4 LDS bufs) ----
// counted vmcnt (6/3/0 tail-aware; TRIG 4/2/0 + lgkmcnt0), one barrier/step,
// T2 K-granule XOR swizzle both-sides.
// TRIG: A-tile is the sinusoid embedding computed in-register (1 sincos + 28 FMA
//       per thread per stage, angle-addition recurrence) and ds_written to the
//       linear A buffer with the SAME source permutation the swizzled gld16
//       would have produced. Eliminates the demb buffer + k_demb entirely.
// SWZ: 1D grid with XCD-chunked bijective remap (m204), bn 4-wide.
// EPI 0: bf16 store. 1: silu(acc+bias)->bf16.
// 2: edge epilogue silu(acc + P[src] + Q[dst] + R[graph]) (cbase = chunk offset)
// 3: residual f32: h += silu(acc+bias)
template<int EPI, bool SWZ, bool TRIG>
__device__ __forceinline__ void gemm_core(
    const u16* __restrict__ A, int lda,
    const u16* __restrict__ B, int ldb,
    int M, int K,
    u16* __restrict__ Cb, float* __restrict__ Cf, int ldc,
    const float* __restrict__ bias,
    int cbase,
    const u16* __restrict__ PQ,
    const int* __restrict__ nodS, const int* __restrict__ dstS,
    const int* __restrict__ n2g, const float* __restrict__ Rp,
    int nwg, const float* __restrict__ fdS)
{
  __shared__ u16 As[4*2048];
  __shared__ u16 Bs[4*4096];
  int bm, bn;
  if constexpr (SWZ){
    int orig = blockIdx.x;
    int q = nwg>>3, r = nwg&7;
    int xcd = orig&7, idx = orig>>3;
    int wg = (xcd<r ? xcd*(q+1) : r*(q+1)+(xcd-r)*q) + idx;   // m204 bijective
    bm = wg>>2; bn = wg&3;
  } else { bm = blockIdx.x; bn = blockIdx.y; }
  const int t = threadIdx.x;
  const int lane = t&63;
  const int wave = t>>6;
  const int wm = wave>>1, wn = wave&1;
  const float TP = 6.283185307179586f;

  f32x4 acc[2][4];
  #pragma unroll
  for (int i=0;i<2;i++)
    #pragma unroll
    for (int j=0;j<4;j++) acc[i][j] = (f32x4){0.f,0.f,0.f,0.f};

  const int sr = t>>2;
  const int sk = (((t&3) ^ ((t>>3)&3)))*8;     // T2 source-side logical granule
  int ar0 = bm*64 + sr; if (ar0 > M-1) ar0 = M-1;
  const u16* Ag0 = TRIG ? nullptr : (A + (size_t)ar0*lda + sk);
  const u16* Bg0 = B + (size_t)(bn*128 + sr)*ldb + sk;
  const u16* Bg1 = B + (size_t)(bn*128 + sr + 64)*ldb + sk;
  u16* As0 = &As[t*8];
  u16* Bs0 = &Bs[t*8];
  u16* Bs1 = &Bs[t*8 + 2048];

  // TRIG per-thread constants: frac_diff components + rotation (sin/cos of 2pi*x_d)
  float fx0=0,fx1=0,fx2=0, ds0=0,dc0=0, ds1=0,dc1=0, ds2=0,dc2=0;
  if constexpr (TRIG){
    const float* fr = fdS + (size_t)(cbase + ar0)*3;
    fx0=fr[0]; fx1=fr[1]; fx2=fr[2];
    __sincosf(TP*fx0,&ds0,&dc0);
    __sincosf(TP*fx1,&ds1,&dc1);
    __sincosf(TP*fx2,&ds2,&dc2);
  }

  const int rg = ((lane>>4) ^ ((lane>>1)&3))*8; // T2 read-side granule
  const u16* ApL = &As[(wm*32 + (lane&15))*32 + rg];
  const u16* BpL = &Bs[(wn*64 + (lane&15))*32 + rg];

  const int nk = K>>5;
  #define STAGEN(kt, b) { const int ko=(kt)<<5; \
      if constexpr (TRIG){ \
        int col = ko + sk; \
        int isc = col>=384; int cc = isc ? col-384 : col; \
        int d = cc>>7; \
        float xx = (d==0)?fx0:((d==1)?fx1:fx2); \
        float dss = (d==0)?ds0:((d==1)?ds1:ds2); \
        float dcc = (d==0)?dc0:((d==1)?dc1:dc2); \
        float w0 = xx*(float)(cc&127); w0 -= rintf(w0); \
        float s_, c_; __sincosf(TP*w0, &s_, &c_); \
        short8 v; \
        _Pragma("unroll") \
        for (int j=0;j<8;j++){ \
          v[j] = (short)f2bf(isc ? c_ : s_); \
          float s2 = s_*dcc + c_*dss; \
          float c2 = c_*dcc - s_*dss; \
          s_ = s2; c_ = c2; } \
        *(short8*)(As0 + (b)*2048) = v; \
      } else { \
        gld16(Ag0+ko, As0+(b)*2048); \
      } \
      gld16(Bg0+ko, Bs0+(b)*4096); \
      gld16(Bg1+ko, Bs1+(b)*4096); }

  STAGEN(0,0)
  STAGEN(1,1)
  STAGEN(2,2)
  for (int ki=0; ki<nk; ++ki){
    const int ahead = nk - ki;
    if constexpr (TRIG){
      if (ahead>2)       asm volatile("s_waitcnt vmcnt(4) lgkmcnt(0)" ::: "memory");
      else if (ahead==2) asm volatile("s_waitcnt vmcnt(2) lgkmcnt(0)" ::: "memory");
      else               asm volatile("s_waitcnt vmcnt(0) lgkmcnt(0)" ::: "memory");
    } else {
      if (ahead>2)       asm volatile("s_waitcnt vmcnt(6)" ::: "memory");
      else if (ahead==2) asm volatile("s_waitcnt vmcnt(3)" ::: "memory");
      else               asm volatile("s_waitcnt vmcnt(0)" ::: "memory");
    }
    __builtin_amdgcn_s_barrier();
    if (ki+3 < nk) STAGEN(ki+3, (ki+3)&3)
    const int ca = (ki&3)*2048, cbb = (ki&3)*4096;
    short8 af[2], bf[4];
    #pragma unroll
    for (int mi=0;mi<2;mi++) af[mi] = *(const short8*)(ApL + ca + mi*512);
    #pragma unroll
    for (int ni=0;ni<4;ni++) bf[ni] = *(const short8*)(BpL + cbb + ni*512);
    #pragma unroll
    for (int mi=0;mi<2;mi++)
      #pragma unroll
      for (int ni=0;ni<4;ni++)
        acc[mi][ni] = __builtin_amdgcn_mfma_f32_16x16x32_bf16(af[mi], bf[ni], acc[mi][ni], 0,0,0);
  }
  #undef STAGEN

  const int c0 = bn*128 + wn*64 + (lane&15);
  const int r0 = bm*64 + wm*32 + ((lane>>4)<<2);

  if constexpr (EPI==0){
    #pragma unroll
    for (int mi=0;mi<2;mi++)
      #pragma unroll
      for (int r=0;r<4;r++){
        int row = r0 + mi*16 + r;
        if (row < M){
          u16* o = Cb + (size_t)row*ldc + c0;
          #pragma unroll
          for (int ni=0;ni<4;ni++) o[ni*16] = f2bf(acc[mi][ni][r]);
        }
      }
  } else if constexpr (EPI==1){
    float bz[4];
    #pragma unroll
    for (int ni=0;ni<4;ni++) bz[ni] = bias[c0 + ni*16];
    #pragma unroll
    for (int mi=0;mi<2;mi++)
      #pragma unroll
      for (int r=0;r<4;r++){
        int row = r0 + mi*16 + r;
        if (row < M){
          u16* o = Cb + (size_t)row*ldc + c0;
          #pragma unroll
          for (int ni=0;ni<4;ni++) o[ni*16] = f2bf(siluf(acc[mi][ni][r]+bz[ni]));
        }
      }
  } else if constexpr (EPI==2){
    #pragma unroll
    for (int mi=0;mi<2;mi++)
      #pragma unroll
      for (int r=0;r<4;r++){
        int row = r0 + mi*16 + r;
        if (row < M){
          int gs = cbase + row;
          int sn = nodS[gs], dn = dstS[gs];
          int g  = n2g[sn];
          const u16* Pp = PQ + (size_t)sn*1024 + c0;
          const u16* Qp = PQ + (size_t)dn*1024 + 512 + c0;
          const float* Rr = Rp + g*512 + c0;
          u16* o = Cb + (size_t)row*ldc + c0;
          #pragma unroll
          for (int ni=0;ni<4;ni++){
            float v = acc[mi][ni][r] + bf2f(Pp[ni*16]) + bf2f(Qp[ni*16]) + Rr[ni*16];
            o[ni*16] = f2bf(siluf(v));
          }
        }
      }
  } else {
    float bz[4];
    #pragma unroll
    for (int ni=0;ni<4;ni++) bz[ni] = bias[c0 + ni*16];
    #pragma unroll
    for (int mi=0;mi<2;mi++)
      #pragma unroll
      for (int r=0;r<4;r++){
        int row = r0 + mi*16 + r;
        if (row < M){
          float* hp = Cf + (size_t)row*ldc + c0;
          #pragma unroll
          for (int ni=0;ni<4;ni++) hp[ni*16] += siluf(acc[mi][ni][r]+bz[ni]);
        }
      }
  }
}

#define GEMM_ARGS const u16* A, int lda, const u16* B, int ldb, int M, int K, \
    u16* Cb, float* Cf, int ldc, const float* bias, int cbase, const u16* PQ, \
    const int* nodS, const int* dstS, const int* n2g, const float* Rp, int nwg, \
    const float* fdS
#define GEMM_PASS A,lda,B,ldb,M,K,Cb,Cf,ldc,bias,cbase,PQ,nodS,dstS,n2g,Rp,nwg,fdS

__global__ __launch_bounds__(256) void g_pq(GEMM_ARGS){ gemm_core<0,false,false>(GEMM_PASS); }
__global__ __launch_bounds__(256) void g_n1(GEMM_ARGS){ gemm_core<1,false,false>(GEMM_PASS); }
__global__ __launch_bounds__(256) void g_n2(GEMM_ARGS){ gemm_core<3,false,false>(GEMM_PASS); }
__global__ __launch_bounds__(256) void g_e1(GEMM_ARGS){ gemm_core<2,true,true>(GEMM_PASS); }
__global__ __launch_bounds__(256) void g_e2(GEMM_ARGS){ gemm_core<1,true,false>(GEMM_PASS); }

// ---------------- small kernels ----------------
__global__ void k_prep(const float* __restrict__ tp, const float* __restrict__ Wt,
                       const float* __restrict__ Wa, const float* __restrict__ ba,
                       float* __restrict__ bias2){
  __shared__ float te[256];
  int t=threadIdx.x;
  te[t] = tp[0]*Wt[t];
  __syncthreads();
  for (int i=t;i<512;i+=256){
    float s = ba[i];
    const float* wr = Wa + (size_t)i*768 + 512;
    for (int j=0;j<256;j++) s += wr[j]*te[j];
    bias2[i]=s;
  }
}

__global__ void k_h0(const float* __restrict__ emb, const float* __restrict__ Wa,
                     const float* __restrict__ bias2, float* __restrict__ h0){
  __shared__ float et[512];
  int ty=blockIdx.x, t=threadIdx.x;
  et[t]=emb[(size_t)ty*512+t]; et[t+256]=emb[(size_t)ty*512+t+256];
  __syncthreads();
  for (int i=t;i<512;i+=256){
    float s=bias2[i];
    const float* wr = Wa + (size_t)i*768;
    for (int k=0;k<512;k++) s += wr[k]*et[k];
    h0[(size_t)ty*512+i]=siluf(s);
  }
}

__global__ void k_inith(const int* __restrict__ at, const float* __restrict__ h0,
                        float* __restrict__ h){
  int total=TN*512;
  for (int i=blockIdx.x*blockDim.x+threadIdx.x; i<total; i+=gridDim.x*blockDim.x){
    int n=i>>9, c=i&511;
    h[i]=h0[(size_t)at[n]*512+c];
  }
}

__global__ void k_count(const int* __restrict__ src, int* __restrict__ counts){
  for (int e=blockIdx.x*blockDim.x+threadIdx.x; e<TE; e+=gridDim.x*blockDim.x)
    atomicAdd(&counts[src[e]],1);
}

__global__ void k_scan(const int* __restrict__ cnt, int* __restrict__ iptr){
  __shared__ int sums[1024];
  const int T=1024, n=TN;
  int t=threadIdx.x;
  const int chunk=(n+T-1)/T;
  int s=0;
  for (int i=0;i<chunk;i++){ int idx=t*chunk+i; if(idx<n) s+=cnt[idx]; }
  sums[t]=s; __syncthreads();
  for (int off=1; off<T; off<<=1){
    int v = (t>=off)? sums[t-off] : 0;
    __syncthreads();
    sums[t]+=v;
    __syncthreads();
  }
  int run = (t==0)?0:sums[t-1];
  for (int i=0;i<chunk;i++){
    int idx=t*chunk+i;
    if(idx<n){ iptr[idx]=run; run+=cnt[idx]; }
  }
  if (t==T-1) iptr[n]=run;
}

__global__ void k_fill(const int* __restrict__ src, const int* __restrict__ dst,
                       const float* __restrict__ fd, const int* __restrict__ iptr,
                       int* __restrict__ slots, int* __restrict__ nodS,
                       int* __restrict__ dstS, float* __restrict__ fdS){
  for (int e=blockIdx.x*blockDim.x+threadIdx.x; e<TE; e+=gridDim.x*blockDim.x){
    int s=src[e];
    int p=atomicAdd(&slots[s],1);
    int gs=iptr[s]+p;
    nodS[gs]=s; dstS[gs]=dst[e];
    fdS[(size_t)gs*3+0]=fd[(size_t)e*3+0];
    fdS[(size_t)gs*3+1]=fd[(size_t)e*3+1];
    fdS[(size_t)gs*3+2]=fd[(size_t)e*3+2];
  }
}

__global__ void k_R(const float* __restrict__ lat, const float* __restrict__ eW1,
                    const float* __restrict__ eb1, float* __restrict__ Rp){
  int total = 2*64*512;
  for (int i=blockIdx.x*blockDim.x+threadIdx.x; i<total; i+=gridDim.x*blockDim.x){
    int l = i>>15;
    int g = (i>>9)&63;
    int o = i&511;
    float s = eb1[l*512+o];
    const float* wr = eW1 + ((size_t)l*512 + o)*1798 + 1024;
    const float* lr = lat + g*6;
    #pragma unroll
    for (int k=0;k<6;k++) s += lr[k]*wr[k];
    Rp[i]=s;
  }
}

struct PackDesc { const float* src; u16* dst; int rows, cols, ld, off; };
struct PackArgs { PackDesc d[12]; };
__global__ void k_pack(PackArgs pa){
  PackDesc d = pa.d[blockIdx.y];
  int total = d.rows*d.cols;
  for (int i = blockIdx.x*blockDim.x + threadIdx.x; i<total; i += gridDim.x*blockDim.x){
    int r = i/d.cols, c = i - r*d.cols;
    d.dst[i] = f2bf(d.src[(size_t)r*d.ld + d.off + c]);
  }
}

__global__ void k_ln(const float* __restrict__ h, const float* __restrict__ g,
                     const float* __restrict__ b, u16* __restrict__ hcat){
  int row = blockIdx.x, t = threadIdx.x;
  const float* hr = h + (size_t)row*512;
  float v0 = hr[t], v1 = hr[t+256];
  float s = v0+v1, ss = v0*v0+v1*v1;
  blockReduce2(s, ss);
  float mean = s*(1.0f/512.0f);
  float var  = ss*(1.0f/512.0f) - mean*mean;
  float rs = rsqrtf(var + 1e-5f);
  u16* o = hcat + (size_t)row*1024;
  o[t]     = f2bf((v0-mean)*rs*g[t]     + b[t]);
  o[t+256] = f2bf((v1-mean)*rs*g[t+256] + b[t+256]);
}

__global__ void k_aggpart(const u16* __restrict__ xc, const int* __restrict__ iptr,
                          int s0, int s1, float* __restrict__ aggf){
  int n=blockIdx.x, t=threadIdx.x;
  int beg=iptr[n], end=iptr[n+1];
  if (beg<s0) beg=s0;
  if (end>s1) end=s1;
  if (beg>=end) return;
  float a0=0.f, a1=0.f;
  for (int i=beg;i<end;i++){
    const u16* xr = xc + (size_t)(i-s0)*512;
    a0 += bf2f(xr[t]); a1 += bf2f(xr[t+256]);
  }
  float* ar = aggf + (size_t)n*512;
  ar[t] += a0; ar[t+256] += a1;
}

__global__ void k_aggfin(const float* __restrict__ aggf, const int* __restrict__ counts,
                         u16* __restrict__ hcat){
  int n=blockIdx.x, t=threadIdx.x;
  int c=counts[n]; if (c<1) c=1;
  float inv = 1.0f/(float)c;
  const float* ar = aggf + (size_t)n*512;
  u16* o = hcat + (size_t)n*1024 + 512;
  o[t]     = f2bf(ar[t]*inv);
  o[t+256] = f2bf(ar[t+256]*inv);
}

// fused aggregation (NCH==1): CSR sum over x rows, normalize, write hcat[512:]
__global__ void k_agg(const u16* __restrict__ x, const int* __restrict__ iptr,
                      u16* __restrict__ hcat){
  int n=blockIdx.x, t=threadIdx.x;
  int beg=iptr[n], end=iptr[n+1];
  float a0=0.f, a1=0.f;
  for (int i=beg;i<end;i++){
    const u16* xr = x + (size_t)i*512;
    a0 += bf2f(xr[t]); a1 += bf2f(xr[t+256]);
  }
  int c=end-beg; if (c<1) c=1;
  float inv = 1.0f/(float)c;
  u16* o = hcat + (size_t)n*1024 + 512;
  o[t]     = f2bf(a0*inv);
  o[t+256] = f2bf(a1*inv);
}

__global__ void k_final(const float* __restrict__ h, const float* __restrict__ g,
                        const float* __restrict__ b, const float* __restrict__ Wc,
                        float* __restrict__ out){
  int row=blockIdx.x, t=threadIdx.x;
  const float* hr = h + (size_t)row*512;
  float v0=hr[t], v1=hr[t+256];
  float s=v0+v1, ss=v0*v0+v1*v1;
  blockReduce2(s,ss);
  float mean=s*(1.0f/512.0f), var=ss*(1.0f/512.0f)-mean*mean, rs=rsqrtf(var+1e-5f);
  float n0=(v0-mean)*rs*g[t]+b[t];
  float n1=(v1-mean)*rs*g[t+256]+b[t+256];
  float p0 = n0*Wc[t]      + n1*Wc[t+256];
  float p1 = n0*Wc[512+t]  + n1*Wc[512+t+256];
  float p2 = n0*Wc[1024+t] + n1*Wc[1024+t+256];
  for (int off=32; off>0; off>>=1){
    p0+=__shfl_down(p0,off,64); p1+=__shfl_down(p1,off,64); p2+=__shfl_down(p2,off,64);
  }
  __shared__ float rp[4][3];
  int lane=t&63, wave=t>>6;
  if (lane==0){ rp[wave][0]=p0; rp[wave][1]=p1; rp[wave][2]=p2; }
  __syncthreads();
  if (t<3) out[(size_t)row*3+t] = rp[0][t]+rp[1][t]+rp[2][t]+rp[3][t];
}

__global__ void k_report(float* out, int n, float val){
  for (int i=blockIdx.x*blockDim.x+threadIdx.x; i<n; i+=gridDim.x*blockDim.x) out[i]=val;
}

extern "C" void kernel_launch(void* const* d_in, const int* in_sizes, int n_in,
                              void* d_out, int out_size, void* d_ws, size_t ws_size,
                              hipStream_t stream)
{
  const int*   atom  = (const int*)  d_in[0];
  const int*   n2g   = (const int*)  d_in[1];
  const int*   eidx  = (const int*)  d_in[2];
  const float* fdiff = (const float*)d_in[3];
  const float* lat   = (const float*)d_in[4];
  const float* tp    = (const float*)d_in[5];
  const float* emb   = (const float*)d_in[6];
  const float* Wt    = (const float*)d_in[7];
  const float* Wa    = (const float*)d_in[8];
  const float* ba    = (const float*)d_in[9];
  const float* lng   = (const float*)d_in[10];
  const float* lnb   = (const float*)d_in[11];
  const float* eW1   = (const float*)d_in[12];
  const float* eb1   = (const float*)d_in[13];
  const float* eW2   = (const float*)d_in[14];
  const float* eb2   = (const float*)d_in[15];
  const float* nW1   = (const float*)d_in[16];
  const float* nb1   = (const float*)d_in[17];
  const float* nW2   = (const float*)d_in[18];
  const float* nb2   = (const float*)d_in[19];
  const float* flng  = (const float*)d_in[20];
  const float* flnb  = (const float*)d_in[21];
  const float* Wc    = (const float*)d_in[22];
  float* out = (float*)d_out;

  // ---- runtime-adaptive workspace layout (no demb buffer anymore) ----
  size_t o = 0;
  auto al = [&](size_t b){ size_t r = o; o = A256(o + b); return r; };
  size_t OH   = al((size_t)TN*512*4);
  size_t OPQ  = al((size_t)TN*1024*2);
  size_t OHC  = al((size_t)TN*1024*2);
  size_t OWAB = al((size_t)2*1024*512*2);
  size_t OW1D = al((size_t)2*512*768*2);
  size_t OW2  = al((size_t)2*512*512*2);
  size_t OWN1 = al((size_t)2*512*1024*2);
  size_t OWN2 = al((size_t)2*512*512*2);
  size_t ORP  = al((size_t)2*64*512*4);
  size_t OH0  = al((size_t)119*512*4);
  size_t OB2  = al(512*4);
  size_t OCNT = al((size_t)TN*4);
  size_t OSLOT= al((size_t)TN*4);
  size_t OIPTR= al((size_t)(TN+1)*4);
  size_t ONOD = al((size_t)(TE+PAD)*4);
  size_t ODST = al((size_t)(TE+PAD)*4);
  size_t OFDS = al((size_t)(TE+PAD)*3*4);
  size_t statEnd = o;

  int nch = 0; int ec = 0;
  size_t OAGG=0, OM=0, OX=0;
  const int cands[4] = {1,2,4,8};
  for (int ci=0; ci<4; ++ci){
    int c = cands[ci];
    o = statEnd;
    size_t e = TE/c;
    size_t ag = (c>1) ? al((size_t)TN*512*4) : 0;
    size_t om = al((e+PAD)*512*2);
    size_t ox = al((e+PAD)*512*2);
    if (o <= ws_size){ nch=c; ec=(int)e; OAGG=ag; OM=om; OX=ox; break; }
  }
  char* ws = (char*)d_ws;
  if (!nch){ k_report<<<64,256,0,stream>>>(out, out_size, (float)(ws_size>>20)); return; }

  float* h    = (float*)(ws+OH);
  u16*   PQ   = (u16*)(ws+OPQ);
  u16*   hcat = (u16*)(ws+OHC);
  float* aggf = (float*)(ws+OAGG);
  u16*   m    = (u16*)(ws+OM);
  u16*   u    = (u16*)(ws+OM);        // overlay: u used only after E2 consumed m
  u16*   x    = (u16*)(ws+OX);
  u16*   Wab  = (u16*)(ws+OWAB);
  u16*   W1d  = (u16*)(ws+OW1D);
  u16*   W2c  = (u16*)(ws+OW2);
  u16*   Wn1  = (u16*)(ws+OWN1);
  u16*   Wn2  = (u16*)(ws+OWN2);
  float* Rp   = (float*)(ws+ORP);
  float* h0   = (float*)(ws+OH0);
  float* b2   = (float*)(ws+OB2);
  int* counts = (int*)(ws+OCNT);
  int* slots  = (int*)(ws+OSLOT);
  int* iptr   = (int*)(ws+OIPTR);
  int* nodS   = (int*)(ws+ONOD);
  int* dstS   = (int*)(ws+ODST);
  float* fdS  = (float*)(ws+OFDS);
  const int* src = eidx;
  const int* dst = eidx + TE;

  hipMemsetAsync(ws+OCNT, 0, OIPTR - OCNT, stream);

  k_prep<<<1,256,0,stream>>>(tp, Wt, Wa, ba, b2);
  k_h0<<<119,256,0,stream>>>(emb, Wa, b2, h0);
  k_inith<<<1024,256,0,stream>>>(atom, h0, h);
  k_count<<<391,256,0,stream>>>(src, counts);
  k_scan<<<1,1024,0,stream>>>(counts, iptr);
  k_fill<<<391,256,0,stream>>>(src, dst, fdiff, iptr, slots, nodS, dstS, fdS);
  k_R<<<256,256,0,stream>>>(lat, eW1, eb1, Rp);

  PackArgs pa;
  for (int l=0;l<2;l++){
    const float* e1 = eW1 + (size_t)l*512*1798;
    pa.d[l*6+0] = {e1, Wab + (size_t)l*1024*512,             512, 512, 1798, 0};
    pa.d[l*6+1] = {e1, Wab + (size_t)l*1024*512 + 512*512,   512, 512, 1798, 512};
    pa.d[l*6+2] = {e1, W1d + (size_t)l*512*768,              512, 768, 1798, 1030};
    pa.d[l*6+3] = {eW2 + (size_t)l*512*512, W2c + (size_t)l*512*512, 512, 512, 512, 0};
    pa.d[l*6+4] = {nW1 + (size_t)l*512*1024, Wn1 + (size_t)l*512*1024, 512, 1024, 1024, 0};
    pa.d[l*6+5] = {nW2 + (size_t)l*512*512, Wn2 + (size_t)l*512*512, 512, 512, 512, 0};
  }
  k_pack<<<dim3(128,12),256,0,stream>>>(pa);

  const int nbmE = (ec+63)/64;
  const int nwgE = nbmE*4;
  const int BMN  = (TN+63)/64;
  const int N0 = 0;

  for (int l=0;l<2;l++){
    k_ln<<<TN,256,0,stream>>>(h, lng+(size_t)l*512, lnb+(size_t)l*512, hcat);
    g_pq<<<dim3(BMN,8),256,0,stream>>>(hcat, 1024, Wab+(size_t)l*1024*512, 512,
        TN, 512, PQ, nullptr, 1024, nullptr, N0, nullptr, nullptr, nullptr, nullptr, nullptr, 0, nullptr);
    if (nch>1) hipMemsetAsync(aggf, 0, (size_t)TN*512*4, stream);
    for (int c=0;c<nch;c++){
      int s0 = c*ec;
      g_e1<<<nwgE,256,0,stream>>>(nullptr, 768, W1d+(size_t)l*512*768, 768,
          ec, 768, m, nullptr, 512, nullptr,
          s0, PQ, nodS, dstS, n2g, Rp+(size_t)l*64*512, nwgE, fdS);
      g_e2<<<nwgE,256,0,stream>>>(m, 512, W2c+(size_t)l*512*512, 512,
          ec, 512, x, nullptr, 512, eb2+(size_t)l*512,
          N0, nullptr, nullptr, nullptr, nullptr, nullptr, nwgE, nullptr);
      if (nch>1) k_aggpart<<<TN,256,0,stream>>>(x, iptr, s0, s0+ec, aggf);
    }
    if (nch==1) k_agg<<<TN,256,0,stream>>>(x, iptr, hcat);
    else        k_aggfin<<<TN,256,0,stream>>>(aggf, counts, hcat);
    g_n1<<<dim3(BMN,4),256,0,stream>>>(hcat, 1024, Wn1+(size_t)l*512*1024, 1024,
        TN, 1024, u, nullptr, 512, nb1+(size_t)l*512,
        N0, nullptr, nullptr, nullptr, nullptr, nullptr, 0, nullptr);
    g_n2<<<dim3(BMN,4),256,0,stream>>>(u, 512, Wn2+(size_t)l*512*512, 512,
        TN, 512, nullptr, h, 512, nb2+(size_t)l*512,
        N0, nullptr, nullptr, nullptr, nullptr, nullptr, 0, nullptr);
  }
  k_final<<<TN,256,0,stream>>>(h, flng, flnb, Wc, out);
}